// Round 9
// baseline (106.023 us; speedup 1.0000x reference)
//
#include <hip/hip_runtime.h>
#include <hip/hip_bf16.h>

typedef __hip_bfloat16 bf16;

// R19: 2-kernel pipeline with every identified relocation tax removed.
//  R18 null result: intra-kernel micro-opts changed nothing (102.32 == 102.31)
//  -> per-kernel dwell is fixed overhead (~16us), only kernel COUNT matters.
//  Prior 2-kernel failures, each now engineered out:
//   R12 tax (sniff x1024 blocks)      -> sniff only in proj; out reads flags.
//   R13 tax (scattered direct W)      -> W staged to LDS per 128-col chunk:
//        coalesced row-major global loads, XOR swizzle c4^((r>>2)&7) on the
//        tile so transposed reads spread bank-quads; tile unioned with red
//        (live at different times) -> 49KB LDS; accumulators persist in regs.
//        W traffic 98KB/block from L2 (< R11's 128KB WT4 reads).
//   R14 tax (shfl butterfly)          -> R11's inner-loop shape kept verbatim.
//   segzero dependency + atomics      -> R12-proven exclusive blkS/blkKV.
//   w_sum: proj tail, 2 entries/block (R13/R18-proven shfl reduce).
// Kernels: proj(512x256) -> out(512x256).
// flags f: 0=f32, 1=bf16, 2=all-zero; flags[13]=any bf16 (output dtype).

__device__ __forceinline__ float ldf(const void* p, int f, long idx) {
    if (f == 0) return ((const float*)p)[idx];
    if (f == 1) {
        unsigned int u = ((unsigned int)((const unsigned short*)p)[idx]) << 16;
        float r; __builtin_memcpy(&r, &u, 4); return r;
    }
    return 0.f;
}

// 4 consecutive elements starting at element idx (idx % 4 == 0).
__device__ __forceinline__ float4 ld4(const void* p, int f, long idx) {
    if (f == 0) return ((const float4*)p)[idx >> 2];
    if (f == 1) {
        const unsigned short* sp = (const unsigned short*)p + idx;
        unsigned int u0 = ((unsigned int)sp[0]) << 16;
        unsigned int u1 = ((unsigned int)sp[1]) << 16;
        unsigned int u2 = ((unsigned int)sp[2]) << 16;
        unsigned int u3 = ((unsigned int)sp[3]) << 16;
        float4 r;
        __builtin_memcpy(&r.x, &u0, 4); __builtin_memcpy(&r.y, &u1, 4);
        __builtin_memcpy(&r.z, &u2, 4); __builtin_memcpy(&r.w, &u3, 4);
        return r;
    }
    return make_float4(0.f, 0.f, 0.f, 0.f);
}

// parallel sniff of all 13 inputs -> sf[0..12]; 2 syncthreads.
__device__ __forceinline__ void sniff13(const void* const* ps, const int* ns,
                                        int tid, unsigned* mall, int* sf) {
    unsigned m = 0;
    for (int t = tid; t < 13 * 64; t += 256) {
        int p = t >> 6, j = t & 63;
        int n16 = ns[p] < 64 ? ns[p] : 64;
        if (j < n16) {
            unsigned short v = ((const unsigned short*)ps[p])[j];
            if (v != 0) m |= (1u << p);
        }
    }
    for (int t = tid; t < 13 * 32; t += 256) {
        int p = t >> 5, jp = t & 31;
        int n16 = ns[p] < 64 ? ns[p] : 64; int npair = n16 >> 1;
        if (jp < npair) {
            const unsigned short* u = (const unsigned short*)ps[p];
            unsigned short lo = u[2 * jp], hi = u[2 * jp + 1];
            int elo = (lo >> 7) & 0xFF, ehi = (hi >> 7) & 0xFF;
            bool lo_ok = (elo >= 64 && elo <= 190) || lo == 0;
            bool hi_ok = (ehi >= 64 && ehi <= 190) || hi == 0;
            if (!(lo_ok && hi_ok)) m |= (1u << (16 + p));
        }
    }
    #pragma unroll
    for (int off = 1; off < 64; off <<= 1) m |= __shfl_xor(m, off);
    if (tid == 0) *mall = 0;
    __syncthreads();
    if ((tid & 63) == 0) atomicOr(mall, m);
    __syncthreads();
    unsigned mm = *mall;
    if (tid < 13) {
        int f;
        if (!((mm >> tid) & 1)) f = 2;
        else f = ((mm >> (16 + tid)) & 1) ? 0 : 1;
        sf[tid] = f;
    }
    __syncthreads();
}

// proj: 8 rows/block (grid 512), 256 threads = 16 o-quads x 16 c-chunks.
// Sniffs; stages x; GEMM via LDS W-tile (4 chunks of 128 cols); writes k_ws,
// r_ws, exclusive blkS/blkKV partials; w_sum tail; block 0 publishes flags.
__global__ __launch_bounds__(256) void proj_kernel(
    const void* x, const void* tw, const void* alpha, const void* beta,
    const void* gamma, const void* Wk, const void* bk, const void* Wv,
    const void* bv, const void* Wr, const void* br, const void* Wo,
    const void* bo,
    int n0, int n1, int n2, int n3, int n4, int n5, int n6, int n7,
    int n8, int n9, int n10, int n11, int n12,
    float* __restrict__ k_ws, float* __restrict__ r_ws,
    float* __restrict__ blkS, float* __restrict__ blkKV,
    float* __restrict__ w_sum, int* __restrict__ flags)
{
    __shared__ float xs[8 * 512];    // 16 KB  x rows
    __shared__ float uni[8192];      // 32 KB  union: W-tile (6144 used) / red
    __shared__ float kred[128], kvred[128], wsred[4];
    __shared__ int sf[16];
    __shared__ unsigned mall;
    int tid = threadIdx.x;
    const void* ps[13] = {x,tw,alpha,beta,gamma,Wk,bk,Wv,bv,Wr,br,Wo,bo};
    int ns[13] = {n0,n1,n2,n3,n4,n5,n6,n7,n8,n9,n10,n11,n12};
    sniff13(ps, ns, tid, &mall, sf);

    if (blockIdx.x == 0 && tid < 14) {
        if (tid == 13) {
            int any16 = 0;
            for (int j = 0; j < 13; ++j) if (sf[j] == 1) any16 = 1;
            flags[13] = any16;
        } else {
            flags[tid] = sf[tid];
        }
    }

    int row0 = blockIdx.x * 8;
    int b = row0 >> 10;
    int lt0 = row0 & 1023;
    int fx = sf[0];

    // ---- stage x rows (time-shifted first half) into LDS ----
    if (fx == 1) {
        const unsigned short* xp = (const unsigned short*)x;
        #pragma unroll
        for (int j = 0; j < 4; ++j) {
            int v = tid + 256 * j;
            int el = v * 4;
            int r = el >> 9, c = el & 511;
            int lt = lt0 + r - ((c < 256) ? 1 : 0);
            float4 f;
            if (lt < 0) f = make_float4(0.f, 0.f, 0.f, 0.f);
            else {
                const unsigned short* sp = xp + ((long)(b * 1024 + lt) * 512 + c);
                unsigned int u0 = ((unsigned int)sp[0]) << 16;
                unsigned int u1 = ((unsigned int)sp[1]) << 16;
                unsigned int u2 = ((unsigned int)sp[2]) << 16;
                unsigned int u3 = ((unsigned int)sp[3]) << 16;
                __builtin_memcpy(&f.x, &u0, 4); __builtin_memcpy(&f.y, &u1, 4);
                __builtin_memcpy(&f.z, &u2, 4); __builtin_memcpy(&f.w, &u3, 4);
            }
            reinterpret_cast<float4*>(xs)[v] = f;
        }
    } else {
        const float* xp = (const float*)x;
        #pragma unroll
        for (int j = 0; j < 4; ++j) {
            int v = tid + 256 * j;
            int el = v * 4;
            int r = el >> 9, c = el & 511;
            int lt = lt0 + r - ((c < 256) ? 1 : 0);
            float4 f;
            if (lt < 0) f = make_float4(0.f, 0.f, 0.f, 0.f);
            else f = *reinterpret_cast<const float4*>(xp + ((long)(b * 1024 + lt) * 512 + c));
            reinterpret_cast<float4*>(xs)[v] = f;
        }
    }
    __syncthreads();

    // ---- GEMM: 4 chunks of 128 cols; W tile in LDS (XOR-swizzled) ----
    int o4 = tid & 15, cc = tid >> 4;
    const float4* xs4 = reinterpret_cast<const float4*>(xs);
    float4* wt4 = reinterpret_cast<float4*>(uni);
    float a0[8], a1[8], a2[8], a3[8];
    #pragma unroll
    for (int r = 0; r < 8; ++r) { a0[r] = a1[r] = a2[r] = a3[r] = 0.f; }
    bool fastW = (sf[5] == 0) && (sf[7] == 0) && (sf[9] == 0);

    for (int ch = 0; ch < 4; ++ch) {
        // stage tile: 48 rows x 32 col-quads (1536 float4 = 24 KB)
        #pragma unroll
        for (int i = 0; i < 6; ++i) {
            int idx = tid + 256 * i;            // < 1536
            int r = idx >> 5, c4 = idx & 31;
            int col = ch * 128 + c4 * 4;
            float4 w;
            if (fastW) {
                const float* Wp = (r < 16) ? (const float*)Wk
                                : (r < 32) ? (const float*)Wv : (const float*)Wr;
                w = *reinterpret_cast<const float4*>(Wp + (long)(r & 15) * 512 + col);
            } else {
                const void* Wp; int fw;
                if (r < 16)      { Wp = Wk; fw = sf[5]; }
                else if (r < 32) { Wp = Wv; fw = sf[7]; }
                else             { Wp = Wr; fw = sf[9]; }
                w = ld4(Wp, fw, (long)(r & 15) * 512 + col);
            }
            wt4[r * 32 + (c4 ^ ((r >> 2) & 7))] = w;
        }
        __syncthreads();
        if (o4 < 12) {
            #pragma unroll
            for (int q = 0; q < 2; ++q) {
                int cql = cc * 2 + q;
                int cq = ch * 32 + cql;
                int sw = cql ^ (o4 & 7);        // (ro>>2)&7 == o4&7 for ro=o4*4+j
                float4 w0 = wt4[(o4 * 4 + 0) * 32 + sw];
                float4 w1 = wt4[(o4 * 4 + 1) * 32 + sw];
                float4 w2 = wt4[(o4 * 4 + 2) * 32 + sw];
                float4 w3 = wt4[(o4 * 4 + 3) * 32 + sw];
                #pragma unroll
                for (int r = 0; r < 8; ++r) {
                    float4 x4 = xs4[r * 128 + cq];
                    a0[r] += x4.x * w0.x + x4.y * w0.y + x4.z * w0.z + x4.w * w0.w;
                    a1[r] += x4.x * w1.x + x4.y * w1.y + x4.z * w1.z + x4.w * w1.w;
                    a2[r] += x4.x * w2.x + x4.y * w2.y + x4.z * w2.z + x4.w * w2.w;
                    a3[r] += x4.x * w3.x + x4.y * w3.y + x4.z * w3.z + x4.w * w3.w;
                }
            }
        }
        __syncthreads();   // tile consumed before next chunk / red overwrite
    }

    // ---- uni becomes red: [cc*8+r][64] partials, only o4<12 columns used ----
    float4* red4 = reinterpret_cast<float4*>(uni);
    if (o4 < 12) {
        #pragma unroll
        for (int r = 0; r < 8; ++r)
            red4[(cc * 8 + r) * 16 + o4] = make_float4(a0[r], a1[r], a2[r], a3[r]);
    }
    __syncthreads();

    // ---- epilogue: k/exp, v partials (exclusive slots), r ----
    const float* red = uni;
    #pragma unroll
    for (int it = 0; it < 2; ++it) {
        int idx = tid + 256 * it;        // < 512
        int o2 = idx & 63, r2 = idx >> 6;
        if (o2 < 48) {
            float S;
            if (o2 < 16)      S = ldf(bk, sf[6], o2);
            else if (o2 < 32) S = ldf(bv, sf[8], o2 - 16);
            else              S = ldf(br, sf[10], o2 - 32);
            #pragma unroll
            for (int cc2 = 0; cc2 < 16; ++cc2)
                S += red[(cc2 * 8 + r2) * 64 + o2];
            long a = (long)(lt0 + r2) * 64 + b * 16 + (o2 & 15);
            if (o2 < 16) {
                k_ws[a] = expf(fminf(fmaxf(S, -60.f), 30.f));
            } else if (o2 < 32) {
                int d = o2 - 16;
                float sk = ldf(bk, sf[6], d);
                #pragma unroll
                for (int cc2 = 0; cc2 < 16; ++cc2)
                    sk += red[(cc2 * 8 + r2) * 64 + d];
                float kk = expf(fminf(fmaxf(sk, -60.f), 30.f));
                kred[d * 8 + r2] = kk;        // exclusive (d,r2) slot
                kvred[d * 8 + r2] = kk * S;   // S == v value here
            } else {
                r_ws[a] = S;
            }
        }
    }
    __syncthreads();
    if (tid < 16) {
        float sk = 0.f, skv = 0.f;
        #pragma unroll
        for (int r = 0; r < 8; ++r) { sk += kred[tid * 8 + r]; skv += kvred[tid * 8 + r]; }
        blkS[(long)blockIdx.x * 16 + tid] = sk;
        blkKV[(long)blockIdx.x * 16 + tid] = skv;
    }

    // ---- w_sum: 2 entries per block (u = 2*bid + g), 128 lanes each ----
    {
        int g = tid >> 7, l = tid & 127;
        int u = blockIdx.x * 2 + g;
        int n = 1024 - u;
        int ftw = sf[1], fbe = sf[3];
        float acc = 0.f;
        for (int s = l; s < n; s += 128)
            acc += ldf(tw, ftw, 1023 - s) * ldf(beta, fbe, u + s);
        #pragma unroll
        for (int off = 32; off > 0; off >>= 1) acc += __shfl_xor(acc, off);
        if ((tid & 63) == 0) wsred[tid >> 6] = acc;
        __syncthreads();
        if ((tid & 127) == 0)
            w_sum[u] = (wsred[g * 2] + wsred[g * 2 + 1]) * ldf(alpha, sf[2], u);
    }
}

// out: 8 rows/block (grid 512). Flags + w_sum from proj; cumk from blkS
// partials + in-block k rows; kvmean from all 128 chunk partials; Wo direct
// with block-uniform dtype branch. (R12-proven body.)
__global__ __launch_bounds__(256) void out_kernel(
    const void* gamma, const void* Wo, const void* bo,
    const float* __restrict__ k_ws, const float* __restrict__ r_ws,
    const float* __restrict__ blkS, const float* __restrict__ blkKV,
    const float* __restrict__ w_sum, const int* __restrict__ flags,
    void* __restrict__ out)
{
    __shared__ float redc[256], redk[256];
    __shared__ float cums[16], kvm[16], kk8[8][16], rr8[8][16], rw[8][16];
    __shared__ int sfl[16];
    int tid = threadIdx.x;
    if (tid < 16) sfl[tid] = flags[tid];

    int row0 = blockIdx.x * 8;
    int b = row0 >> 10;
    int t0 = row0 & 1023;                 // 8-aligned
    int nch = t0 >> 3;                    // full 8-row chunks before t0
    long base = (long)b * 16;

    // chunk-parallel partials: prefix-S over nch chunks, kv over all 128
    {
        int d = tid & 15, lane = tid >> 4;
        float pc = 0.f, pk = 0.f;
        for (int ch = lane; ch < nch; ch += 16) pc += blkS[((long)b * 128 + ch) * 16 + d];
        for (int ch = lane; ch < 128; ch += 16) pk += blkKV[((long)b * 128 + ch) * 16 + d];
        redc[tid] = pc; redk[tid] = pk;
    }
    // this block's 8 rows of k and r into LDS
    if (tid < 128) {
        int rl = tid >> 4, dd = tid & 15;
        kk8[rl][dd] = k_ws[(long)(t0 + rl) * 64 + base + dd];
    } else {
        int tt = tid - 128; int rl = tt >> 4, dd = tt & 15;
        rr8[rl][dd] = r_ws[(long)(t0 + rl) * 64 + base + dd];
    }
    __syncthreads();
    if (tid < 16) {
        float c = 0.f, kv = 0.f;
        #pragma unroll
        for (int ln = 0; ln < 16; ++ln) { c += redc[ln * 16 + tid]; kv += redk[ln * 16 + tid]; }
        cums[tid] = c;
        kvm[tid] = kv * (1.0f / 1024.0f);
    }
    __syncthreads();

    // per-row rwkv
    if (tid < 128) {
        int rl = tid >> 4, o = tid & 15;
        float ck = cums[o];
        for (int i = 0; i <= rl; ++i) ck += kk8[i][o];
        rw[rl][o] = rr8[rl][o] * w_sum[t0 + rl] * kvm[o] / (ck + 1e-8f);
    }
    __syncthreads();

    // Wo dot + gamma + store (block-uniform dtype branch)
    int fWo = sfl[11], fbo = sfl[12], fga = sfl[4], any16 = sfl[13];
    if (fWo == 0) {
        const float4* Wq = reinterpret_cast<const float4*>(Wo);
        #pragma unroll
        for (int it = 0; it < 2; ++it) {
            int idx = tid + 256 * it;          // < 512
            int rl = idx >> 6, o = idx & 63;
            int t = t0 + rl;
            float acc = ldf(bo, fbo, o);
            #pragma unroll
            for (int j = 0; j < 4; ++j) {
                float4 w = Wq[o * 4 + j];
                acc += rw[rl][4 * j + 0] * w.x + rw[rl][4 * j + 1] * w.y +
                       rw[rl][4 * j + 2] * w.z + rw[rl][4 * j + 3] * w.w;
            }
            float val = acc * ldf(gamma, fga, t);
            long oa = (long)(row0 + rl) * 64 + o;
            if (any16) ((bf16*)out)[oa] = __float2bfloat16(val);
            else       ((float*)out)[oa] = val;
        }
    } else {
        #pragma unroll
        for (int it = 0; it < 2; ++it) {
            int idx = tid + 256 * it;
            int rl = idx >> 6, o = idx & 63;
            int t = t0 + rl;
            float acc = ldf(bo, fbo, o);
            #pragma unroll
            for (int j = 0; j < 4; ++j) {
                float4 w = ld4(Wo, fWo, (long)o * 16 + 4 * j);
                acc += rw[rl][4 * j + 0] * w.x + rw[rl][4 * j + 1] * w.y +
                       rw[rl][4 * j + 2] * w.z + rw[rl][4 * j + 3] * w.w;
            }
            float val = acc * ldf(gamma, fga, t);
            long oa = (long)(row0 + rl) * 64 + o;
            if (any16) ((bf16*)out)[oa] = __float2bfloat16(val);
            else       ((float*)out)[oa] = val;
        }
    }
}

extern "C" void kernel_launch(void* const* d_in, const int* in_sizes, int n_in,
                              void* d_out, int out_size, void* d_ws, size_t ws_size,
                              hipStream_t stream) {
    // insertion order (confirmed R4): x, time_w, time_alpha, time_beta,
    // time_gamma, Wk, bk, Wv, bv, Wr, br, Wo, bo
    const void* x     = d_in[0];
    const void* tw    = d_in[1];
    const void* alpha = d_in[2];
    const void* beta  = d_in[3];
    const void* gamma = d_in[4];
    const void* Wk    = d_in[5];
    const void* bk    = d_in[6];
    const void* Wv    = d_in[7];
    const void* bv    = d_in[8];
    const void* Wr    = d_in[9];
    const void* br    = d_in[10];
    const void* Wo    = d_in[11];
    const void* bo    = d_in[12];

    float* ws    = (float*)d_ws;
    float* k_ws  = ws;              // 65536  [t][b*16+d]  raw k
    float* r_ws  = ws + 65536;      // 65536  [t][b*16+d]
    float* blkS  = ws + 131072;     // 8192   [512][16] per-proj-block sum(k)
    float* blkKV = ws + 139264;     // 8192   [512][16] per-proj-block sum(k*v)
    float* w_sum = ws + 147456;     // 1024
    int*   flags = (int*)(ws + 148480);  // 16 ints

    proj_kernel<<<512, 256, 0, stream>>>(
        x, tw, alpha, beta, gamma, Wk, bk, Wv, bv, Wr, br, Wo, bo,
        in_sizes[0], in_sizes[1], in_sizes[2], in_sizes[3], in_sizes[4],
        in_sizes[5], in_sizes[6], in_sizes[7], in_sizes[8], in_sizes[9],
        in_sizes[10], in_sizes[11], in_sizes[12],
        k_ws, r_ws, blkS, blkKV, w_sum, flags);
    out_kernel<<<512, 256, 0, stream>>>(
        gamma, Wo, bo, k_ws, r_ws, blkS, blkKV, w_sum, flags, (void*)d_out);
}